// Round 10
// baseline (33.494 us; speedup 1.0000x reference)
//
#include <hip/hip_runtime.h>
#include <hip/hip_fp16.h>

typedef _Float16 f16x8 __attribute__((ext_vector_type(8)));
typedef _Float16 f16x2 __attribute__((ext_vector_type(2)));
typedef __fp16   fp16v2 __attribute__((ext_vector_type(2)));
typedef float floatx4 __attribute__((ext_vector_type(4)));
typedef float floatx2 __attribute__((ext_vector_type(2)));

#define NEG 0.01f
#define KL_C (-2.8025850929940457f)

// ws layout (float units)
// [0 .. 131071]   W1 f16 MFMA B-fragments: 64 f x 512 uint4 (512 KB)
#define W0HOFF 131072        // 4096 halves
#define B0HOFF 133120        // 4096 halves
#define B1OFF  135168        // 4096 f32
#define W2HOFF 139264        // 4096 halves (f16, interleaved pairs over n)
#define B2OFF  143360        // 64 f32
#define KLPOFF 143424        // 264 f32 partials

__device__ __forceinline__ f16x2 cvt2(float a, float b) {
    union { fp16v2 p; f16x2 h; } u;
    u.p = __builtin_amdgcn_cvt_pkrtz(a, b);
    return u.h;
}

// prep grid: blocks 0..255 = (feature f = bx>>2, quarter q = bx&3);
// blocks 256..263: small tensors eff + KL, d_out = bias init.
__global__ void bayesnam_prep(const float* __restrict__ wmu0, const float* __restrict__ wls0,
                              const float* __restrict__ bmu0, const float* __restrict__ bls0,
                              const float* __restrict__ ew0,  const float* __restrict__ eb0,
                              const float* __restrict__ wmu1, const float* __restrict__ wls1,
                              const float* __restrict__ bmu1, const float* __restrict__ bls1,
                              const float* __restrict__ ew1,  const float* __restrict__ eb1,
                              const float* __restrict__ wmu2, const float* __restrict__ wls2,
                              const float* __restrict__ bmu2, const float* __restrict__ bls2,
                              const float* __restrict__ ew2,  const float* __restrict__ eb2,
                              const float* __restrict__ bias,
                              float* __restrict__ ws, float* __restrict__ out) {
    const int tid = threadIdx.x;
    const int bx  = blockIdx.x;
    __shared__ float red[256];
    if (bx < 256) {
        const int f = bx >> 2;
        const int q = bx & 3;
        __shared__ float w1s[16 * 65];
        const size_t base = (size_t)f * 4096 + (size_t)q * 1024;
        float klacc = 0.f;
        #pragma unroll
        for (int i = 0; i < 4; ++i) {
            const int idx = i * 256 + tid;           // klocal*64 + col
            const float m = wmu1[base + idx];
            const float l = wls1[base + idx];
            const float e = ew1[base + idx];
            const float ex = expf(l);
            w1s[(idx >> 6) * 65 + (idx & 63)] = fmaf(ex, e, m);
            klacc += (KL_C - l) + 50.f * fmaf(ex, ex, m * m);
        }
        red[tid] = klacc * 0.000244140625f;          // 1/4096 (per-feature mean)
        __syncthreads();
        for (int s = 128; s > 0; s >>= 1) {
            if (tid < s) red[tid] += red[tid + s];
            __syncthreads();
        }
        if (tid == 0) ws[KLPOFF + bx] = red[0];
        // fragment pack: layout [f][kk][n][lane][8 f16]
        if (tid < 128) {
            const int n   = tid >> 5;
            const int ls  = tid & 31;
            const int s   = ls >> 4;                 // 8-row group within quarter
            const int l15 = ls & 15;
            const int lg  = 2 * (q & 1) + s;
            const int lane = lg * 16 + l15;
            const int kk  = q >> 1;
            const int col = n * 16 + l15;
            union { _Float16 h[8]; uint4 u; } fr;
            #pragma unroll
            for (int j = 0; j < 8; ++j) fr.h[j] = (_Float16)w1s[(8 * s + j) * 65 + col];
            ((uint4*)ws)[(size_t)f * 512 + kk * 256 + n * 64 + lane] = fr.u;
        }
    } else {
        float klacc = 0.f;
        _Float16* w0h = (_Float16*)(ws + W0HOFF);
        _Float16* b0h = (_Float16*)(ws + B0HOFF);
        _Float16* w2h = (_Float16*)(ws + W2HOFF);
        for (int idx = (bx - 256) * 256 + tid; idx < 16448; idx += 2048) {
            const float *mu, *ls, *ew;
            int j, kind; float scale;
            if (idx < 4096)       { j = idx;         mu = wmu0; ls = wls0; ew = ew0; scale = 0.015625f; kind = 0; }
            else if (idx < 8192)  { j = idx - 4096;  mu = bmu0; ls = bls0; ew = eb0; scale = 0.015625f; kind = 1; }
            else if (idx < 12288) { j = idx - 8192;  mu = bmu1; ls = bls1; ew = eb1; scale = 0.015625f; kind = 2; }
            else if (idx < 16384) { j = idx - 12288; mu = wmu2; ls = wls2; ew = ew2; scale = 0.015625f; kind = 3; }
            else                  { j = idx - 16384; mu = bmu2; ls = bls2; ew = eb2; scale = 1.0f;      kind = 4; }
            const float m = mu[j], l = ls[j], e = ew[j];
            const float ex = expf(l);
            const float w  = fmaf(ex, e, m);
            if (kind == 0)      w0h[j] = (_Float16)w;
            else if (kind == 1) b0h[j] = (_Float16)w;
            else if (kind == 2) ws[B1OFF + j] = w;
            else if (kind == 3) {
                // interleave pairs over n within each 32-hidden half:
                // slot = f*64 + (h>>5)*32 + (h&15)*2 + ((h>>4)&1)
                const int h = j & 63;
                w2h[(j & ~63) | ((h >> 5) << 5) | ((h & 15) << 1) | ((h >> 4) & 1)] = (_Float16)w;
            }
            else                ws[B2OFF + j] = w;
            klacc += scale * ((KL_C - l) + 50.f * fmaf(ex, ex, m * m));
        }
        const float bv = bias[0];
        for (int i = (bx - 256) * 256 + tid; i < 16384; i += 2048) out[i] = bv;
        red[tid] = klacc;
        __syncthreads();
        for (int s = 128; s > 0; s >>= 1) {
            if (tid < s) red[tid] += red[tid + s];
            __syncthreads();
        }
        if (tid == 0) ws[KLPOFF + 256 + (bx - 256)] = red[0];
    }
}

// Main: per wave 32 rows x 64 hidden, 2 features per block (32 chunks).
// 16 KB LDS + <=64 VGPR (n-split accumulator) -> 8 blocks/CU, 8 waves/SIMD.
// Packed f16 epilogue (cvt_pkrtz + pk_mul/pk_max/pk_fma).
__global__ __launch_bounds__(256, 8) void bayesnam_main(const float* __restrict__ fin,
                                                        const float* __restrict__ ws,
                                                        float* __restrict__ out) {
    __shared__ uint4 fragLDS[1024];                  // 16 KB: 2 features x 8 KB
    const int tid = threadIdx.x;
    const int l   = tid & 63;
    const int wid = tid >> 6;
    const int l15 = l & 15;
    const int lg  = l >> 4;
    const int rowbase = blockIdx.x * 128 + wid * 32;
    const int f0 = blockIdx.y * 2;

    // stage fragments: per-lane global src, wave-uniform LDS dest (linear)
    {
        const char* gsrc = (const char*)ws + (size_t)f0 * 8192;
        #pragma unroll
        for (int i = 0; i < 4; ++i) {
            const int chunk = (wid * 4 + i) * 1024;
            __builtin_amdgcn_global_load_lds(
                (const __attribute__((address_space(1))) unsigned int*)(gsrc + chunk + l * 16),
                (__attribute__((address_space(3))) unsigned int*)((char*)fragLDS + chunk),
                16, 0, 0);
        }
    }

    // KL finalize (prep partials ready: same-stream ordering)
    if (blockIdx.x == 0 && blockIdx.y == 0 && tid < 64) {
        float k = 0.f;
        #pragma unroll
        for (int i = 0; i < 5; ++i) {
            const int p = tid + i * 64;
            if (p < 264) k += ws[KLPOFF + p];
        }
        k += __shfl_xor(k, 32, 64); k += __shfl_xor(k, 16, 64); k += __shfl_xor(k, 8, 64);
        k += __shfl_xor(k, 4, 64);  k += __shfl_xor(k, 2, 64);  k += __shfl_xor(k, 1, 64);
        if (tid == 0) out[16384] = k;
    }

    const _Float16* __restrict__ w0h = (const _Float16*)(ws + W0HOFF);
    const _Float16* __restrict__ b0h = (const _Float16*)(ws + B0HOFF);
    const _Float16* __restrict__ w2h = (const _Float16*)(ws + W2HOFF);
    const _Float16 negh = (_Float16)0.01f;
    const f16x2 neg2 = {(_Float16)0.01f, (_Float16)0.01f};

    const floatx2 x0v = *(const floatx2*)(fin + (size_t)(rowbase + l15) * 64 + f0);
    const floatx2 x1v = *(const floatx2*)(fin + (size_t)(rowbase + 16 + l15) * 64 + f0);

    __syncthreads();                                 // staging complete

    f16x2 ypk[2][4];
    #pragma unroll
    for (int r = 0; r < 2; ++r)
        #pragma unroll
        for (int q = 0; q < 4; ++q) ypk[r][q] = f16x2{(_Float16)0.f, (_Float16)0.f};
    float b2sum = 0.f;

    #pragma unroll 1
    for (int fi = 0; fi < 2; ++fi) {
        const int f = f0 + fi;
        const _Float16 x0h = (_Float16)x0v[fi];
        const _Float16 x1h = (_Float16)x1v[fi];

        // layer-0: build A-fragments for both k-halves (live across nh loop)
        f16x8 a0[2], a1[2];
        #pragma unroll
        for (int kk = 0; kk < 2; ++kk) {
            const int kb = kk * 32 + lg * 8;
            union HU { uint4 u; f16x8 v; } wu, bu;
            wu.u = *(const uint4*)(w0h + f * 64 + kb);
            bu.u = *(const uint4*)(b0h + f * 64 + kb);
            f16x8 t0 = wu.v * x0h + bu.v;
            a0[kk] = __builtin_elementwise_max(t0, t0 * negh);
            f16x8 t1 = wu.v * x1h + bu.v;
            a1[kk] = __builtin_elementwise_max(t1, t1 * negh);
        }

        const float* b1p = ws + B1OFF + f * 64;
        #pragma unroll 1
        for (int nh = 0; nh < 2; ++nh) {
            floatx4 acc[2][2];
            #pragma unroll
            for (int n2 = 0; n2 < 2; ++n2) {
                const float bv = b1p[(nh * 2 + n2) * 16 + l15];
                acc[0][n2] = floatx4{bv, bv, bv, bv};
                acc[1][n2] = floatx4{bv, bv, bv, bv};
            }
            #pragma unroll
            for (int kk = 0; kk < 2; ++kk) {
                #pragma unroll
                for (int n2 = 0; n2 < 2; ++n2) {
                    union HU { uint4 u; f16x8 v; } bf;
                    bf.u = fragLDS[fi * 512 + kk * 256 + (nh * 2 + n2) * 64 + l];
                    acc[0][n2] = __builtin_amdgcn_mfma_f32_16x16x32_f16(a0[kk], bf.v, acc[0][n2], 0, 0, 0);
                    acc[1][n2] = __builtin_amdgcn_mfma_f32_16x16x32_f16(a1[kk], bf.v, acc[1][n2], 0, 0, 0);
                }
            }
            // packed epilogue: pair over n2, leaky in f16, pk_fma into ypk
            const f16x2 w2pair = *(const f16x2*)(w2h + f * 64 + nh * 32 + l15 * 2);
            #pragma unroll
            for (int r = 0; r < 2; ++r)
                #pragma unroll
                for (int q = 0; q < 4; ++q) {
                    f16x2 h2 = (r == 0) ? cvt2(acc[0][0][q], acc[0][1][q])
                                        : cvt2(acc[1][0][q], acc[1][1][q]);
                    f16x2 lk = __builtin_elementwise_max(h2, h2 * neg2);
                    ypk[r][q] = lk * w2pair + ypk[r][q];
                }
        }
        b2sum += ws[B2OFF + f];
    }

    // unpack + reduce over 16 column-lanes (C layout: col = l&15, row = lg*4+q)
    #pragma unroll
    for (int r = 0; r < 2; ++r)
        #pragma unroll
        for (int q = 0; q < 4; ++q) {
            float v = (float)ypk[r][q][0] + (float)ypk[r][q][1];
            v += __shfl_xor(v, 1, 64);
            v += __shfl_xor(v, 2, 64);
            v += __shfl_xor(v, 4, 64);
            v += __shfl_xor(v, 8, 64);
            if (l15 == 0)
                atomicAdd(&out[rowbase + r * 16 + lg * 4 + q], v + b2sum);
        }
}

extern "C" void kernel_launch(void* const* d_in, const int* in_sizes, int n_in,
                              void* d_out, int out_size, void* d_ws, size_t ws_size,
                              hipStream_t stream) {
    const float* fin  = (const float*)d_in[0];
    const float* wmu0 = (const float*)d_in[1];
    const float* wls0 = (const float*)d_in[2];
    const float* bmu0 = (const float*)d_in[3];
    const float* bls0 = (const float*)d_in[4];
    const float* ew0  = (const float*)d_in[5];
    const float* eb0  = (const float*)d_in[6];
    const float* wmu1 = (const float*)d_in[7];
    const float* wls1 = (const float*)d_in[8];
    const float* bmu1 = (const float*)d_in[9];
    const float* bls1 = (const float*)d_in[10];
    const float* ew1  = (const float*)d_in[11];
    const float* eb1  = (const float*)d_in[12];
    const float* wmu2 = (const float*)d_in[13];
    const float* wls2 = (const float*)d_in[14];
    const float* bmu2 = (const float*)d_in[15];
    const float* bls2 = (const float*)d_in[16];
    const float* ew2  = (const float*)d_in[17];
    const float* eb2  = (const float*)d_in[18];
    const float* bias = (const float*)d_in[19];

    float* ws  = (float*)d_ws;
    float* out = (float*)d_out;

    hipLaunchKernelGGL(bayesnam_prep, dim3(264), dim3(256), 0, stream,
                       wmu0, wls0, bmu0, bls0, ew0, eb0,
                       wmu1, wls1, bmu1, bls1, ew1, eb1,
                       wmu2, wls2, bmu2, bls2, ew2, eb2,
                       bias, ws, out);

    hipLaunchKernelGGL(bayesnam_main, dim3(128, 32), dim3(256), 0, stream,
                       fin, ws, out);
}

// Round 11
// 29.304 us; speedup vs baseline: 1.1430x; 1.1430x over previous
//
#include <hip/hip_runtime.h>
#include <hip/hip_fp16.h>

typedef _Float16 f16x8 __attribute__((ext_vector_type(8)));
typedef _Float16 f16x2 __attribute__((ext_vector_type(2)));
typedef __fp16   fp16v2 __attribute__((ext_vector_type(2)));
typedef float floatx4 __attribute__((ext_vector_type(4)));

#define NEG 0.01f
#define KL_C (-2.8025850929940457f)

// ws layout (float units)
// [0 .. 131071]   W1 f16 MFMA B-fragments: 64 f x 512 uint4 (512 KB)
#define W0HOFF 131072        // 4096 halves
#define B0HOFF 133120        // 4096 halves
#define B1OFF  135168        // 4096 f32
#define W2HOFF 139264        // 4096 halves (f16, interleaved pairs over n)
#define B2OFF  143360        // 64 f32
#define KLPOFF 143424        // 520 f32 partials

__device__ __forceinline__ f16x2 cvt2(float a, float b) {
    union { fp16v2 p; f16x2 h; } u;
    u.p = __builtin_amdgcn_cvt_pkrtz(a, b);
    return u.h;
}

// prep grid: blocks 0..511 = (feature f = bx>>3, 8-row group g = bx&7):
//   W1 eff (fp32) + KL partial + f16 fragment pack (one (kk,lg) slice).
// blocks 512..519: small tensors eff + KL, d_out = bias init.
__global__ void bayesnam_prep(const float* __restrict__ wmu0, const float* __restrict__ wls0,
                              const float* __restrict__ bmu0, const float* __restrict__ bls0,
                              const float* __restrict__ ew0,  const float* __restrict__ eb0,
                              const float* __restrict__ wmu1, const float* __restrict__ wls1,
                              const float* __restrict__ bmu1, const float* __restrict__ bls1,
                              const float* __restrict__ ew1,  const float* __restrict__ eb1,
                              const float* __restrict__ wmu2, const float* __restrict__ wls2,
                              const float* __restrict__ bmu2, const float* __restrict__ bls2,
                              const float* __restrict__ ew2,  const float* __restrict__ eb2,
                              const float* __restrict__ bias,
                              float* __restrict__ ws, float* __restrict__ out) {
    const int tid = threadIdx.x;
    const int bx  = blockIdx.x;
    __shared__ float red[256];
    if (bx < 512) {
        const int f = bx >> 3;
        const int g = bx & 7;                        // absolute k rows g*8 .. g*8+7
        __shared__ float w1s[8 * 65];
        const size_t base = (size_t)f * 4096 + (size_t)g * 512;
        float klacc = 0.f;
        #pragma unroll
        for (int i = 0; i < 2; ++i) {
            const int idx = i * 256 + tid;           // row*64 + col
            const float m = wmu1[base + idx];
            const float l = wls1[base + idx];
            const float e = ew1[base + idx];
            const float ex = expf(l);
            w1s[(idx >> 6) * 65 + (idx & 63)] = fmaf(ex, e, m);
            klacc += (KL_C - l) + 50.f * fmaf(ex, ex, m * m);
        }
        red[tid] = klacc * 0.000244140625f;          // 1/4096 (per-feature mean)
        __syncthreads();
        for (int s = 128; s > 0; s >>= 1) {
            if (tid < s) red[tid] += red[tid + s];
            __syncthreads();
        }
        if (tid == 0) ws[KLPOFF + bx] = red[0];
        // fragment pack: this block covers kk = g>>2, lg = g&3 (k = kk*32+lg*8+j)
        if (tid < 64) {
            const int n   = tid >> 4;
            const int l15 = tid & 15;
            const int kk  = g >> 2;
            const int lg  = g & 3;
            const int col = n * 16 + l15;
            union { _Float16 h[8]; uint4 u; } fr;
            #pragma unroll
            for (int j = 0; j < 8; ++j) fr.h[j] = (_Float16)w1s[j * 65 + col];
            ((uint4*)ws)[(size_t)f * 512 + kk * 256 + n * 64 + lg * 16 + l15] = fr.u;
        }
    } else {
        float klacc = 0.f;
        _Float16* w0h = (_Float16*)(ws + W0HOFF);
        _Float16* b0h = (_Float16*)(ws + B0HOFF);
        _Float16* w2h = (_Float16*)(ws + W2HOFF);
        for (int idx = (bx - 512) * 256 + tid; idx < 16448; idx += 2048) {
            const float *mu, *ls, *ew;
            int j, kind; float scale;
            if (idx < 4096)       { j = idx;         mu = wmu0; ls = wls0; ew = ew0; scale = 0.015625f; kind = 0; }
            else if (idx < 8192)  { j = idx - 4096;  mu = bmu0; ls = bls0; ew = eb0; scale = 0.015625f; kind = 1; }
            else if (idx < 12288) { j = idx - 8192;  mu = bmu1; ls = bls1; ew = eb1; scale = 0.015625f; kind = 2; }
            else if (idx < 16384) { j = idx - 12288; mu = wmu2; ls = wls2; ew = ew2; scale = 0.015625f; kind = 3; }
            else                  { j = idx - 16384; mu = bmu2; ls = bls2; ew = eb2; scale = 1.0f;      kind = 4; }
            const float m = mu[j], l = ls[j], e = ew[j];
            const float ex = expf(l);
            const float w  = fmaf(ex, e, m);
            if (kind == 0)      w0h[j] = (_Float16)w;
            else if (kind == 1) b0h[j] = (_Float16)w;
            else if (kind == 2) ws[B1OFF + j] = w;
            else if (kind == 3) {
                // pair-interleave over n: slot = f*64 + (h>>5)*32 + (h&15)*2 + ((h>>4)&1)
                const int h = j & 63;
                w2h[(j & ~63) | ((h >> 5) << 5) | ((h & 15) << 1) | ((h >> 4) & 1)] = (_Float16)w;
            }
            else                ws[B2OFF + j] = w;
            klacc += scale * ((KL_C - l) + 50.f * fmaf(ex, ex, m * m));
        }
        const float bv = bias[0];
        for (int i = (bx - 512) * 256 + tid; i < 16384; i += 2048) out[i] = bv;
        red[tid] = klacc;
        __syncthreads();
        for (int s = 128; s > 0; s >>= 1) {
            if (tid < s) red[tid] += red[tid + s];
            __syncthreads();
        }
        if (tid == 0) ws[KLPOFF + 512 + (bx - 512)] = red[0];
    }
}

// Main: per wave 32 rows x 64 hidden, 4 features per block (16 chunks).
// R8 base structure; feature loop unroll-2 for ILP; packed f16 epilogue.
__global__ __launch_bounds__(256, 4) void bayesnam_main(const float* __restrict__ fin,
                                                        const float* __restrict__ ws,
                                                        float* __restrict__ out) {
    __shared__ uint4 fragLDS[2048];                  // 32 KB: 4 features x 8 KB
    const int tid = threadIdx.x;
    const int l   = tid & 63;
    const int wid = tid >> 6;
    const int l15 = l & 15;
    const int lg  = l >> 4;
    const int rowbase = blockIdx.x * 128 + wid * 32;
    const int f0 = blockIdx.y * 4;

    // stage fragments: per-lane global src, wave-uniform LDS dest (linear)
    {
        const char* gsrc = (const char*)ws + (size_t)f0 * 8192;
        #pragma unroll
        for (int i = 0; i < 8; ++i) {
            const int chunk = (wid * 8 + i) * 1024;
            __builtin_amdgcn_global_load_lds(
                (const __attribute__((address_space(1))) unsigned int*)(gsrc + chunk + l * 16),
                (__attribute__((address_space(3))) unsigned int*)((char*)fragLDS + chunk),
                16, 0, 0);
        }
    }

    // KL finalize (prep partials ready: same-stream ordering)
    if (blockIdx.x == 0 && blockIdx.y == 0 && tid < 64) {
        float k = 0.f;
        #pragma unroll
        for (int i = 0; i < 9; ++i) {
            const int p = tid + i * 64;
            if (p < 520) k += ws[KLPOFF + p];
        }
        k += __shfl_xor(k, 32, 64); k += __shfl_xor(k, 16, 64); k += __shfl_xor(k, 8, 64);
        k += __shfl_xor(k, 4, 64);  k += __shfl_xor(k, 2, 64);  k += __shfl_xor(k, 1, 64);
        if (tid == 0) out[16384] = k;
    }

    const _Float16* __restrict__ w0h = (const _Float16*)(ws + W0HOFF);
    const _Float16* __restrict__ b0h = (const _Float16*)(ws + B0HOFF);
    const _Float16* __restrict__ w2h = (const _Float16*)(ws + W2HOFF);
    const f16x2 neg2 = {(_Float16)0.01f, (_Float16)0.01f};

    const floatx4 x0v = *(const floatx4*)(fin + (size_t)(rowbase + l15) * 64 + f0);
    const floatx4 x1v = *(const floatx4*)(fin + (size_t)(rowbase + 16 + l15) * 64 + f0);

    __syncthreads();                                 // staging complete

    f16x2 ypk[2][4];
    #pragma unroll
    for (int r = 0; r < 2; ++r)
        #pragma unroll
        for (int q = 0; q < 4; ++q) ypk[r][q] = f16x2{(_Float16)0.f, (_Float16)0.f};
    float b2sum = 0.f;

    #pragma unroll 2
    for (int fi = 0; fi < 4; ++fi) {
        const int f = f0 + fi;
        const _Float16 x0h = (_Float16)x0v[fi];
        const _Float16 x1h = (_Float16)x1v[fi];

        floatx4 acc[2][4];
        {
            const float* b1p = ws + B1OFF + f * 64;
            #pragma unroll
            for (int n = 0; n < 4; ++n) {
                const float bv = b1p[n * 16 + l15];
                acc[0][n] = floatx4{bv, bv, bv, bv};
                acc[1][n] = floatx4{bv, bv, bv, bv};
            }
        }

        #pragma unroll
        for (int kk = 0; kk < 2; ++kk) {
            const int kb = kk * 32 + lg * 8;
            union HU { uint4 u; f16x8 v; } wu, bu;
            wu.u = *(const uint4*)(w0h + f * 64 + kb);
            bu.u = *(const uint4*)(b0h + f * 64 + kb);
            f16x8 t0 = wu.v * x0h + bu.v;
            f16x8 a0 = __builtin_elementwise_max(t0, t0 * neg2[0]);
            f16x8 t1 = wu.v * x1h + bu.v;
            f16x8 a1 = __builtin_elementwise_max(t1, t1 * neg2[0]);

            #pragma unroll
            for (int n = 0; n < 4; ++n) {
                union HU2 { uint4 u; f16x8 v; } bf;
                bf.u = fragLDS[(fi * 8 + kk * 4 + n) * 64 + l];
                acc[0][n] = __builtin_amdgcn_mfma_f32_16x16x32_f16(a0, bf.v, acc[0][n], 0, 0, 0);
                acc[1][n] = __builtin_amdgcn_mfma_f32_16x16x32_f16(a1, bf.v, acc[1][n], 0, 0, 0);
            }
        }

        // packed f16 epilogue: pairs (n0,n1) and (n2,n3)
        const f16x2 w2p0 = *(const f16x2*)(w2h + f * 64 + l15 * 2);
        const f16x2 w2p1 = *(const f16x2*)(w2h + f * 64 + 32 + l15 * 2);
        #pragma unroll
        for (int r = 0; r < 2; ++r)
            #pragma unroll
            for (int q = 0; q < 4; ++q) {
                f16x2 h0 = cvt2(acc[r][0][q], acc[r][1][q]);
                f16x2 h1 = cvt2(acc[r][2][q], acc[r][3][q]);
                f16x2 lk0 = __builtin_elementwise_max(h0, h0 * neg2);
                f16x2 lk1 = __builtin_elementwise_max(h1, h1 * neg2);
                ypk[r][q] = lk0 * w2p0 + ypk[r][q];
                ypk[r][q] = lk1 * w2p1 + ypk[r][q];
            }
        b2sum += ws[B2OFF + f];
    }

    // unpack + reduce over 16 column-lanes (C layout: col = l&15, row = lg*4+q)
    #pragma unroll
    for (int r = 0; r < 2; ++r)
        #pragma unroll
        for (int q = 0; q < 4; ++q) {
            float v = (float)ypk[r][q][0] + (float)ypk[r][q][1];
            v += __shfl_xor(v, 1, 64);
            v += __shfl_xor(v, 2, 64);
            v += __shfl_xor(v, 4, 64);
            v += __shfl_xor(v, 8, 64);
            if (l15 == 0)
                atomicAdd(&out[rowbase + r * 16 + lg * 4 + q], v + b2sum);
        }
}

extern "C" void kernel_launch(void* const* d_in, const int* in_sizes, int n_in,
                              void* d_out, int out_size, void* d_ws, size_t ws_size,
                              hipStream_t stream) {
    const float* fin  = (const float*)d_in[0];
    const float* wmu0 = (const float*)d_in[1];
    const float* wls0 = (const float*)d_in[2];
    const float* bmu0 = (const float*)d_in[3];
    const float* bls0 = (const float*)d_in[4];
    const float* ew0  = (const float*)d_in[5];
    const float* eb0  = (const float*)d_in[6];
    const float* wmu1 = (const float*)d_in[7];
    const float* wls1 = (const float*)d_in[8];
    const float* bmu1 = (const float*)d_in[9];
    const float* bls1 = (const float*)d_in[10];
    const float* ew1  = (const float*)d_in[11];
    const float* eb1  = (const float*)d_in[12];
    const float* wmu2 = (const float*)d_in[13];
    const float* wls2 = (const float*)d_in[14];
    const float* bmu2 = (const float*)d_in[15];
    const float* bls2 = (const float*)d_in[16];
    const float* ew2  = (const float*)d_in[17];
    const float* eb2  = (const float*)d_in[18];
    const float* bias = (const float*)d_in[19];

    float* ws  = (float*)d_ws;
    float* out = (float*)d_out;

    hipLaunchKernelGGL(bayesnam_prep, dim3(520), dim3(256), 0, stream,
                       wmu0, wls0, bmu0, bls0, ew0, eb0,
                       wmu1, wls1, bmu1, bls1, ew1, eb1,
                       wmu2, wls2, bmu2, bls2, ew2, eb2,
                       bias, ws, out);

    hipLaunchKernelGGL(bayesnam_main, dim3(128, 16), dim3(256), 0, stream,
                       fin, ws, out);
}